// Round 17
// baseline (543.450 us; speedup 1.0000x reference)
//
#include <hip/hip_runtime.h>
#include <hip/hip_bf16.h>
#include <math.h>

// DeepSeekMoE: T=4096, H=1024, F=4096, E=8, top-2 sigmoid routing.
// Round 17: r16 base (538us best). Single lever: L3-warm weight staging --
// convert split per-GEMM (w1 converted right before gemm1, w2 right before
// gemm2) so each GEMM's B-weights are L3-resident when staged (2-phase loop is
// staging-latency-bound; L3 hit ~200cy vs HBM ~900cy, m126).
// Weight layout reordered to w1s|w1e|w2s|w2e (contiguous per convert).
// Closed lanes: 8-phase (r4/r6/m232), fused convert (r5/r8-r10), atomic
// combine (r11), 64^2 tile (r14), B-panel-major mapping (r15).

#define T_TOK 4096
#define H_DIM 1024
#define F_DIM 4096
#define NEXP  8
#define RT    (2 * T_TOK)
#define RPAD  512

// worst-case flat grid sizes (fixed for graph capture); BM=128 tiles: 32 shared
// + max 72 expert M-tiles = 104.
#define GT_TILES 104
#define G1_GRID  (GT_TILES * 32)   // NB1 = F/128 = 32
#define G2_GRID  (GT_TILES * 8)    // NB2 = H/128 = 8

typedef __bf16 bf16_t;
typedef __bf16 bf16x8 __attribute__((ext_vector_type(8)));
typedef float  f32x4  __attribute__((ext_vector_type(4)));
typedef unsigned short u16x8 __attribute__((ext_vector_type(8)));
typedef unsigned short u16x4 __attribute__((ext_vector_type(4)));

__device__ __forceinline__ unsigned short f2bf(float f) {
  union { bf16_t b; unsigned short u; } cv;
  cv.b = (bf16_t)f;
  return cv.u;
}

__device__ __forceinline__ float bf2f(unsigned short u) {
  union { bf16_t b; unsigned short u; } cv;
  cv.u = u;
  return (float)cv.b;
}

__device__ __forceinline__ float gelu_exact(float v) {
  return 0.5f * v * (1.0f + erff(v * 0.70710678118654752f));
}

// bijective XCD swizzle (m204)
__device__ __forceinline__ int xcd_swizzle(int orig, int nwg) {
  const int q = nwg >> 3, r = nwg & 7;
  const int xcd = orig & 7, idx = orig >> 3;
  return (xcd < r ? xcd * (q + 1) : r * (q + 1) + (xcd - r) * q) + idx;
}

// ---------------------------------------------------------------- small kernels

// two source tensors (shared|expert) -> one contiguous bf16 dst; optional
// meta-zero in block 0 (first convert only).
__global__ void convert2_kernel(const float* __restrict__ s0, const float* __restrict__ s1,
                                unsigned short* __restrict__ dst,
                                long n0, long nt, int* __restrict__ meta) {
  if (meta != nullptr && blockIdx.x == 0 && threadIdx.x < 64) meta[threadIdx.x] = 0;
  long i = (long)blockIdx.x * blockDim.x + threadIdx.x;
  const long stride = (long)gridDim.x * blockDim.x;
  for (; i < nt; i += stride) {
    const float* s; long j;
    if (i < n0) { s = s0; j = i; }
    else        { s = s1; j = i - n0; }
    const f32x4* sp = (const f32x4*)s + j * 2;
    f32x4 v0 = sp[0], v1 = sp[1];
    u16x8 o;
    #pragma unroll
    for (int k = 0; k < 4; ++k) { o[k] = f2bf(v0[k]); o[4 + k] = f2bf(v1[k]); }
    *(u16x8*)(dst + i * 8) = o;
  }
}

// one wave per token: 8 gate scores -> sigmoid -> top2; also emits x in bf16
__global__ void gate_kernel(const float* __restrict__ x, const float* __restrict__ gw,
                            const float* __restrict__ gb, const float* __restrict__ rb,
                            unsigned short* __restrict__ x_bf,
                            int* __restrict__ tok_e, float* __restrict__ tok_w,
                            int* __restrict__ counts) {
  int tkn = blockIdx.x;
  int lane = threadIdx.x;
  float acc[NEXP];
  #pragma unroll
  for (int e = 0; e < NEXP; ++e) acc[e] = 0.f;
  const float* xr = x + (long)tkn * H_DIM;
  unsigned short* xbr = x_bf + (long)tkn * H_DIM;
  for (int k = lane; k < H_DIM; k += 64) {
    float xv = xr[k];
    xbr[k] = f2bf(xv);
    #pragma unroll
    for (int e = 0; e < NEXP; ++e) acc[e] += xv * gw[e * H_DIM + k];
  }
  #pragma unroll
  for (int off = 32; off > 0; off >>= 1) {
    #pragma unroll
    for (int e = 0; e < NEXP; ++e) acc[e] += __shfl_xor(acc[e], off, 64);
  }
  if (lane == 0) {
    float s[NEXP];
    #pragma unroll
    for (int e = 0; e < NEXP; ++e)
      s[e] = 1.f / (1.f + expf(-(acc[e] + gb[e] + rb[e])));
    int e0 = 0;
    #pragma unroll
    for (int e = 1; e < NEXP; ++e) if (s[e] > s[e0]) e0 = e;
    int e1 = (e0 == 0) ? 1 : 0;
    #pragma unroll
    for (int e = 0; e < NEXP; ++e) if (e != e0 && e != e1 && s[e] > s[e1]) e1 = e;
    tok_e[2 * tkn] = e0;  tok_e[2 * tkn + 1] = e1;
    tok_w[2 * tkn] = s[e0]; tok_w[2 * tkn + 1] = s[e1];
    atomicAdd(&counts[e0], 1);
    atomicAdd(&counts[e1], 1);
  }
}

// merged scan+build: single block; thread 0 scans counts -> offs + BM=128
// tile table; then 256 threads bucket all tokens via LDS cursors.
__global__ void scanbuild_kernel(const int* __restrict__ counts,
                                 const int* __restrict__ tok_e, const float* __restrict__ tok_w,
                                 int* __restrict__ offs_g, int* __restrict__ tt_g,
                                 int* __restrict__ btok, float* __restrict__ bw,
                                 int* __restrict__ tokpos) {
  __shared__ int offs_s[NEXP], cur_s[NEXP];
  const int t = threadIdx.x;
  if (t == 0) {
    int o = 0, a = 0;
    for (int e = 0; e < NEXP; ++e) {
      offs_s[e] = o; offs_g[e] = o;
      tt_g[e] = a;
      a += (counts[e] + 127) >> 7;
      o += counts[e];
    }
    tt_g[8] = a;
    tt_g[9] = a + (T_TOK >> 7);
  }
  if (t < NEXP) cur_s[t] = 0;
  __syncthreads();
  for (int tkn = t; tkn < T_TOK; tkn += 256) {
    #pragma unroll
    for (int k = 0; k < 2; ++k) {
      int e = tok_e[2 * tkn + k];
      int p = offs_s[e] + atomicAdd(&cur_s[e], 1);
      btok[p] = tkn;
      bw[p] = tok_w[2 * tkn + k];
      tokpos[2 * tkn + k] = p;
    }
  }
}

// out += rout_bf16[p0] + rout_bf16[p1]  (f32 accumulate)
__global__ void combine_kernel(float* __restrict__ out, const unsigned short* __restrict__ rout,
                               const int* __restrict__ tokpos) {
  int tkn = blockIdx.x, c = threadIdx.x;   // 256 threads * 4 elems
  int p0 = tokpos[2 * tkn], p1 = tokpos[2 * tkn + 1];
  u16x4 a = *(const u16x4*)(rout + (long)p0 * H_DIM + c * 4);
  u16x4 b = *(const u16x4*)(rout + (long)p1 * H_DIM + c * 4);
  f32x4* o = (f32x4*)out + (long)tkn * 256;
  f32x4 v = o[c];
  #pragma unroll
  for (int j = 0; j < 4; ++j) v[j] += bf2f(a[j]) + bf2f(b[j]);
  o[c] = v;
}

// ---------------------------------------------------------------- grouped GEMM1
// Flat grid, mt-major mapping (r13-proven). 128x128 tile, BK=32, 512 thr /
// 8 waves (2Mx4N, acc[4][2]), 32KB LDS, 2-phase. A rows resolved once per
// thread via btok (gather fused). C = gelu(A@B^T + bias) bf16. K=1024, N=4096.
__global__ __launch_bounds__(512)
void moe_gemm1(const unsigned short* __restrict__ x_bf,
               const unsigned short* __restrict__ Wsh, const unsigned short* __restrict__ Wrt,
               const float* __restrict__ bsh, const float* __restrict__ brt,
               unsigned short* __restrict__ Csh, unsigned short* __restrict__ Crt,
               const int* __restrict__ btok,
               const int* __restrict__ cnts, const int* __restrict__ offs,
               const int* __restrict__ tt) {
  __shared__ __align__(16) unsigned short lds[2][2][128][32];   // 32 KB
  const int wid = xcd_swizzle(blockIdx.x, G1_GRID);
  const int mt = wid >> 5, nb = wid & 31;
  if (mt >= tt[9]) return;
  int z = 0;
  while (mt >= tt[z + 1]) ++z;
  const int mlocal = mt - tt[z];

  const unsigned short* Bp;
  const float* bias;
  unsigned short* C;
  int mcnt;
  const unsigned short* srcA;
  const int t = threadIdx.x;
  {
    const int r0 = mlocal * 128 + (t >> 2);
    if (z == NEXP) {
      Bp = Wsh; bias = bsh; C = Csh; mcnt = T_TOK;
      srcA = x_bf + (long)r0 * H_DIM;
    } else {
      const int off = offs[z];
      mcnt = cnts[z];
      Bp = Wrt + (long)z * F_DIM * H_DIM;
      bias = brt + z * F_DIM;
      C = Crt + (long)off * F_DIM;
      int g0 = off + r0;
      if (g0 > RT - 1) g0 = RT - 1;            // clamped: tail rows epilogue-masked
      srcA = x_bf + (long)btok[g0] * H_DIM;
    }
  }

  f32x4 acc[4][2] = {};
  const int nk = H_DIM >> 5;   // 32 K-steps
  const int ch = (t & 3) * 8;

  auto stage = [&](int kt, int buf) {
    const int row = t >> 2;
    const unsigned short* ga = srcA + kt * 32 + ch;
    const unsigned short* gb = Bp + (long)(nb * 128 + row) * H_DIM + kt * 32 + ch;
    unsigned short* la = &lds[buf][0][0][0] + t * 8;
    unsigned short* lb = &lds[buf][1][0][0] + t * 8;
    __builtin_amdgcn_global_load_lds((const __attribute__((address_space(1))) unsigned int*)ga,
                                     (__attribute__((address_space(3))) unsigned int*)la, 16, 0, 0);
    __builtin_amdgcn_global_load_lds((const __attribute__((address_space(1))) unsigned int*)gb,
                                     (__attribute__((address_space(3))) unsigned int*)lb, 16, 0, 0);
  };

  const int l = t & 63;
  const int w = t >> 6;                       // 8 waves: 2M x 4N
  const int wr = (w >> 2) * 64, wc = (w & 3) * 32;
  const int lr = l & 15, lk = (l >> 4) * 8;

  auto compute = [&](int buf) {
    bf16x8 a[4], b[2];
    #pragma unroll
    for (int m = 0; m < 4; ++m) a[m] = *(const bf16x8*)&lds[buf][0][wr + m * 16 + lr][lk];
    #pragma unroll
    for (int n = 0; n < 2; ++n) b[n] = *(const bf16x8*)&lds[buf][1][wc + n * 16 + lr][lk];
    #pragma unroll
    for (int m = 0; m < 4; ++m)
      #pragma unroll
      for (int n = 0; n < 2; ++n)
        acc[m][n] = __builtin_amdgcn_mfma_f32_16x16x32_bf16(a[m], b[n], acc[m][n], 0, 0, 0);
  };

  stage(0, 0);
  asm volatile("s_waitcnt vmcnt(0)" ::: "memory");
  __syncthreads();
  for (int kt = 0; kt < nk - 1; ++kt) {
    const int cur = kt & 1;
    stage(kt + 1, cur ^ 1);
    compute(cur);
    asm volatile("s_waitcnt vmcnt(0)" ::: "memory");
    __syncthreads();
  }
  compute((nk - 1) & 1);

  // epilogue: C/D layout col=lane&15, row=(lane>>4)*4+j (m89-verified)
  #pragma unroll
  for (int m = 0; m < 4; ++m) {
    #pragma unroll
    for (int n = 0; n < 2; ++n) {
      const int col = nb * 128 + wc + n * 16 + lr;
      const float bc = bias[col];
      #pragma unroll
      for (int j = 0; j < 4; ++j) {
        const int lrow = mlocal * 128 + wr + m * 16 + (l >> 4) * 4 + j;
        if (lrow >= mcnt) continue;
        float v = acc[m][n][j] + bc;
        C[(long)lrow * F_DIM + col] = f2bf(gelu_exact(v));
      }
    }
  }
}

// ---------------------------------------------------------------- grouped GEMM2
// Flat grid, mt-major mapping (r13-proven). 128x128, BK=32, 8 waves (512 thr,
// 2Mx4N, acc[4][2]), 2-phase. shared -> out (f32); routed -> rout (bf16, *bw).
// K=4096, N=1024, NB=8.
__global__ __launch_bounds__(512)
void moe_gemm2(const unsigned short* __restrict__ hbuf,
               const unsigned short* __restrict__ Wsh, const unsigned short* __restrict__ Wrt,
               const float* __restrict__ bsh, const float* __restrict__ brt,
               float* __restrict__ out, unsigned short* __restrict__ rout,
               const float* __restrict__ bwgt,
               const int* __restrict__ cnts, const int* __restrict__ offs,
               const int* __restrict__ tt) {
  __shared__ __align__(16) unsigned short lds[2][2][128][32];   // 32 KB
  const int wid = xcd_swizzle(blockIdx.x, G2_GRID);
  const int mt = wid >> 3, nb = wid & 7;
  if (mt >= tt[9]) return;
  int z = 0;
  while (mt >= tt[z + 1]) ++z;
  const int mlocal = mt - tt[z];

  const unsigned short* A;
  const unsigned short* Bp;
  const float* bias;
  const float* rs = nullptr;
  unsigned short* Crt = nullptr;
  int mcnt;
  if (z == NEXP) {
    A = hbuf; Bp = Wsh; bias = bsh; mcnt = T_TOK;
  } else {
    const int off = offs[z];
    mcnt = cnts[z];
    A = hbuf + ((long)T_TOK + off) * F_DIM;
    Bp = Wrt + (long)z * H_DIM * F_DIM;
    bias = brt + z * H_DIM;
    Crt = rout + (long)off * H_DIM;
    rs = bwgt + off;
  }

  const int t = threadIdx.x;
  f32x4 acc[4][2] = {};
  const int nk = F_DIM >> 5;   // 128 K-steps

  auto stage = [&](int kt, int buf) {
    const int row = t >> 2;
    const int ch = (t & 3) * 8;
    const unsigned short* ga = A + (long)(mlocal * 128 + row) * F_DIM + kt * 32 + ch;
    const unsigned short* gb = Bp + (long)(nb * 128 + row) * F_DIM + kt * 32 + ch;
    unsigned short* la = &lds[buf][0][0][0] + t * 8;
    unsigned short* lb = &lds[buf][1][0][0] + t * 8;
    __builtin_amdgcn_global_load_lds((const __attribute__((address_space(1))) unsigned int*)ga,
                                     (__attribute__((address_space(3))) unsigned int*)la, 16, 0, 0);
    __builtin_amdgcn_global_load_lds((const __attribute__((address_space(1))) unsigned int*)gb,
                                     (__attribute__((address_space(3))) unsigned int*)lb, 16, 0, 0);
  };

  const int l = t & 63;
  const int w = t >> 6;                       // 8 waves: 2M x 4N
  const int wr = (w >> 2) * 64, wc = (w & 3) * 32;
  const int lr = l & 15, lk = (l >> 4) * 8;

  auto compute = [&](int buf) {
    bf16x8 a[4], b[2];
    #pragma unroll
    for (int m = 0; m < 4; ++m) a[m] = *(const bf16x8*)&lds[buf][0][wr + m * 16 + lr][lk];
    #pragma unroll
    for (int n = 0; n < 2; ++n) b[n] = *(const bf16x8*)&lds[buf][1][wc + n * 16 + lr][lk];
    #pragma unroll
    for (int m = 0; m < 4; ++m)
      #pragma unroll
      for (int n = 0; n < 2; ++n)
        acc[m][n] = __builtin_amdgcn_mfma_f32_16x16x32_bf16(a[m], b[n], acc[m][n], 0, 0, 0);
  };

  stage(0, 0);
  asm volatile("s_waitcnt vmcnt(0)" ::: "memory");
  __syncthreads();
  for (int kt = 0; kt < nk - 1; ++kt) {
    const int cur = kt & 1;
    stage(kt + 1, cur ^ 1);
    compute(cur);
    asm volatile("s_waitcnt vmcnt(0)" ::: "memory");
    __syncthreads();
  }
  compute((nk - 1) & 1);

  const bool routed = (z != NEXP);
  #pragma unroll
  for (int m = 0; m < 4; ++m) {
    #pragma unroll
    for (int n = 0; n < 2; ++n) {
      const int col = nb * 128 + wc + n * 16 + lr;
      const float bc = bias[col];
      #pragma unroll
      for (int j = 0; j < 4; ++j) {
        const int lrow = mlocal * 128 + wr + m * 16 + (l >> 4) * 4 + j;
        if (lrow >= mcnt) continue;
        float v = acc[m][n][j] + bc;
        if (routed) Crt[(long)lrow * H_DIM + col] = f2bf(v * rs[lrow]);
        else        out[(long)lrow * H_DIM + col] = v;
      }
    }
  }
}

// ---------------------------------------------------------------- host

extern "C" void kernel_launch(void* const* d_in, const int* in_sizes, int n_in,
                              void* d_out, int out_size, void* d_ws, size_t ws_size,
                              hipStream_t stream) {
  const float* x   = (const float*)d_in[0];
  const float* gw  = (const float*)d_in[1];
  const float* gb  = (const float*)d_in[2];
  const float* rb  = (const float*)d_in[3];
  const float* sw1 = (const float*)d_in[4];
  const float* sb1 = (const float*)d_in[5];
  const float* sw2 = (const float*)d_in[6];
  const float* sb2 = (const float*)d_in[7];
  const float* ew1 = (const float*)d_in[8];
  const float* eb1 = (const float*)d_in[9];
  const float* ew2 = (const float*)d_in[10];
  const float* eb2 = (const float*)d_in[11];

  char* wsp = (char*)d_ws;
  size_t o = 0;
  auto alloc = [&](size_t b) -> void* {
    void* p = wsp + o;
    o = (o + b + 255) & ~(size_t)255;
    return p;
  };
  unsigned short* x_bf = (unsigned short*)alloc((size_t)T_TOK * H_DIM * 2);
  // weight layout: w1s|w1e contiguous (convert #1), then w2s|w2e (convert #2)
  unsigned short* w1s  = (unsigned short*)alloc((size_t)(1 + NEXP) * F_DIM * H_DIM * 2);
  unsigned short* w2s  = (unsigned short*)alloc((size_t)(1 + NEXP) * H_DIM * F_DIM * 2);
  unsigned short* w1e  = w1s + (size_t)F_DIM * H_DIM;
  unsigned short* w2e  = w2s + (size_t)H_DIM * F_DIM;
  unsigned short* hbuf = (unsigned short*)alloc((size_t)(T_TOK + RT + RPAD) * F_DIM * 2);
  unsigned short* rout = (unsigned short*)alloc((size_t)RT * H_DIM * 2);
  int*   tok_e  = (int*)alloc(2 * T_TOK * 4);
  float* tok_w  = (float*)alloc(2 * T_TOK * 4);
  int*   tokpos = (int*)alloc(2 * T_TOK * 4);
  int*   btok   = (int*)alloc(RT * 4);
  float* bw     = (float*)alloc(RT * 4);
  int*   meta   = (int*)alloc(1024);
  int* counts = meta, *offs = meta + 16;
  int* ttof = meta + 32;
  (void)ws_size; (void)in_sizes; (void)n_in; (void)out_size;

  float* out = (float*)d_out;

  const long NW1 = (long)F_DIM * H_DIM / 8;          // shared w1 groups
  const long NW1T = NW1 * (1 + NEXP);                // + expert w1
  const long NW2 = (long)H_DIM * F_DIM / 8;
  const long NW2T = NW2 * (1 + NEXP);

  // convert w1 (zero meta) right before gemm1 -> w1 bf16 L3-warm for staging
  convert2_kernel<<<4096, 256, 0, stream>>>(sw1, ew1, w1s, NW1, NW1T, meta);
  gate_kernel<<<T_TOK, 64, 0, stream>>>(x, gw, gb, rb, x_bf, tok_e, tok_w, counts);
  scanbuild_kernel<<<1, 256, 0, stream>>>(counts, tok_e, tok_w, offs, ttof,
                                          btok, bw, tokpos);

  // GEMM1: K=1024, N=4096; 128^2 8-wave; gather fused; mt-major mapping.
  moe_gemm1<<<G1_GRID, 512, 0, stream>>>(
      x_bf, w1s, w1e, sb1, eb1,
      hbuf, hbuf + (size_t)T_TOK * F_DIM, btok, counts, offs, ttof);

  // convert w2 right before gemm2 -> w2 bf16 L3-warm
  convert2_kernel<<<4096, 256, 0, stream>>>(sw2, ew2, w2s, NW2, NW2T, nullptr);

  // GEMM2: K=4096, N=1024; 128^2 8-wave; mt-major mapping; routed out bf16.
  moe_gemm2<<<G2_GRID, 512, 0, stream>>>(
      hbuf, w2s, w2e, sb2, eb2, out, rout, bw, counts, offs, ttof);

  combine_kernel<<<T_TOK, 256, 0, stream>>>(out, rout, tokpos);
}

// Round 18
// 539.594 us; speedup vs baseline: 1.0071x; 1.0071x over previous
//
#include <hip/hip_runtime.h>
#include <hip/hip_bf16.h>
#include <math.h>

// DeepSeekMoE: T=4096, H=1024, F=4096, E=8, top-2 sigmoid routing.
// Round 18 = r16 exactly (session best, 538us). r17's L3-warm convert split
// was null-to-negative (FETCH 236->152MB but dur unchanged -> 2-phase loop is
// drain-structure-bound, not staging-latency-bound). All lanes now closed:
// 8-phase (r4/r6/m232), fused convert (r5/r8-r10), atomic combine (r11),
// 64^2 tile (r14), B-panel-major (r15), L3-warm staging (r17).
// Structure: mt-major flat balanced grids, 128^2 tile / 8 waves / 24 waves/CU
// (measured optimum of the {tile,waves} surface), gather fused into gemm1
// A-staging, rout bf16, merged scan+build, convert4+meta-zero merge.

#define T_TOK 4096
#define H_DIM 1024
#define F_DIM 4096
#define NEXP  8
#define RT    (2 * T_TOK)
#define RPAD  512

// worst-case flat grid sizes (fixed for graph capture); BM=128 tiles: 32 shared
// + max 72 expert M-tiles = 104.
#define GT_TILES 104
#define G1_GRID  (GT_TILES * 32)   // NB1 = F/128 = 32
#define G2_GRID  (GT_TILES * 8)    // NB2 = H/128 = 8

typedef __bf16 bf16_t;
typedef __bf16 bf16x8 __attribute__((ext_vector_type(8)));
typedef float  f32x4  __attribute__((ext_vector_type(4)));
typedef unsigned short u16x8 __attribute__((ext_vector_type(8)));
typedef unsigned short u16x4 __attribute__((ext_vector_type(4)));

__device__ __forceinline__ unsigned short f2bf(float f) {
  union { bf16_t b; unsigned short u; } cv;
  cv.b = (bf16_t)f;
  return cv.u;
}

__device__ __forceinline__ float bf2f(unsigned short u) {
  union { bf16_t b; unsigned short u; } cv;
  cv.u = u;
  return (float)cv.b;
}

__device__ __forceinline__ float gelu_exact(float v) {
  return 0.5f * v * (1.0f + erff(v * 0.70710678118654752f));
}

// bijective XCD swizzle (m204)
__device__ __forceinline__ int xcd_swizzle(int orig, int nwg) {
  const int q = nwg >> 3, r = nwg & 7;
  const int xcd = orig & 7, idx = orig >> 3;
  return (xcd < r ? xcd * (q + 1) : r * (q + 1) + (xcd - r) * q) + idx;
}

// ---------------------------------------------------------------- small kernels

// all four weight tensors -> contiguous bf16 dst (w1s|w2s|w1e|w2e);
// block 0 also zeroes the meta block -- replaces zero_kernel.
__global__ void convert4_kernel(const float* __restrict__ s0, const float* __restrict__ s1,
                                const float* __restrict__ s2, const float* __restrict__ s3,
                                unsigned short* __restrict__ dst, int* __restrict__ meta) {
  if (blockIdx.x == 0 && threadIdx.x < 64) meta[threadIdx.x] = 0;
  const long N0 = (long)F_DIM * H_DIM / 8;
  const long N1 = N0 + (long)H_DIM * F_DIM / 8;
  const long N2 = N1 + (long)NEXP * F_DIM * H_DIM / 8;
  const long NT = N2 + (long)NEXP * H_DIM * F_DIM / 8;
  long i = (long)blockIdx.x * blockDim.x + threadIdx.x;
  const long stride = (long)gridDim.x * blockDim.x;
  for (; i < NT; i += stride) {
    const float* s; long j;
    if (i < N0)      { s = s0; j = i; }
    else if (i < N1) { s = s1; j = i - N0; }
    else if (i < N2) { s = s2; j = i - N1; }
    else             { s = s3; j = i - N2; }
    const f32x4* sp = (const f32x4*)s + j * 2;
    f32x4 v0 = sp[0], v1 = sp[1];
    u16x8 o;
    #pragma unroll
    for (int k = 0; k < 4; ++k) { o[k] = f2bf(v0[k]); o[4 + k] = f2bf(v1[k]); }
    *(u16x8*)(dst + i * 8) = o;
  }
}

// one wave per token: 8 gate scores -> sigmoid -> top2; also emits x in bf16
__global__ void gate_kernel(const float* __restrict__ x, const float* __restrict__ gw,
                            const float* __restrict__ gb, const float* __restrict__ rb,
                            unsigned short* __restrict__ x_bf,
                            int* __restrict__ tok_e, float* __restrict__ tok_w,
                            int* __restrict__ counts) {
  int tkn = blockIdx.x;
  int lane = threadIdx.x;
  float acc[NEXP];
  #pragma unroll
  for (int e = 0; e < NEXP; ++e) acc[e] = 0.f;
  const float* xr = x + (long)tkn * H_DIM;
  unsigned short* xbr = x_bf + (long)tkn * H_DIM;
  for (int k = lane; k < H_DIM; k += 64) {
    float xv = xr[k];
    xbr[k] = f2bf(xv);
    #pragma unroll
    for (int e = 0; e < NEXP; ++e) acc[e] += xv * gw[e * H_DIM + k];
  }
  #pragma unroll
  for (int off = 32; off > 0; off >>= 1) {
    #pragma unroll
    for (int e = 0; e < NEXP; ++e) acc[e] += __shfl_xor(acc[e], off, 64);
  }
  if (lane == 0) {
    float s[NEXP];
    #pragma unroll
    for (int e = 0; e < NEXP; ++e)
      s[e] = 1.f / (1.f + expf(-(acc[e] + gb[e] + rb[e])));
    int e0 = 0;
    #pragma unroll
    for (int e = 1; e < NEXP; ++e) if (s[e] > s[e0]) e0 = e;
    int e1 = (e0 == 0) ? 1 : 0;
    #pragma unroll
    for (int e = 0; e < NEXP; ++e) if (e != e0 && e != e1 && s[e] > s[e1]) e1 = e;
    tok_e[2 * tkn] = e0;  tok_e[2 * tkn + 1] = e1;
    tok_w[2 * tkn] = s[e0]; tok_w[2 * tkn + 1] = s[e1];
    atomicAdd(&counts[e0], 1);
    atomicAdd(&counts[e1], 1);
  }
}

// merged scan+build: single block; thread 0 scans counts -> offs + BM=128
// tile table; then 256 threads bucket all tokens via LDS cursors.
__global__ void scanbuild_kernel(const int* __restrict__ counts,
                                 const int* __restrict__ tok_e, const float* __restrict__ tok_w,
                                 int* __restrict__ offs_g, int* __restrict__ tt_g,
                                 int* __restrict__ btok, float* __restrict__ bw,
                                 int* __restrict__ tokpos) {
  __shared__ int offs_s[NEXP], cur_s[NEXP];
  const int t = threadIdx.x;
  if (t == 0) {
    int o = 0, a = 0;
    for (int e = 0; e < NEXP; ++e) {
      offs_s[e] = o; offs_g[e] = o;
      tt_g[e] = a;
      a += (counts[e] + 127) >> 7;
      o += counts[e];
    }
    tt_g[8] = a;
    tt_g[9] = a + (T_TOK >> 7);
  }
  if (t < NEXP) cur_s[t] = 0;
  __syncthreads();
  for (int tkn = t; tkn < T_TOK; tkn += 256) {
    #pragma unroll
    for (int k = 0; k < 2; ++k) {
      int e = tok_e[2 * tkn + k];
      int p = offs_s[e] + atomicAdd(&cur_s[e], 1);
      btok[p] = tkn;
      bw[p] = tok_w[2 * tkn + k];
      tokpos[2 * tkn + k] = p;
    }
  }
}

// out += rout_bf16[p0] + rout_bf16[p1]  (f32 accumulate)
__global__ void combine_kernel(float* __restrict__ out, const unsigned short* __restrict__ rout,
                               const int* __restrict__ tokpos) {
  int tkn = blockIdx.x, c = threadIdx.x;   // 256 threads * 4 elems
  int p0 = tokpos[2 * tkn], p1 = tokpos[2 * tkn + 1];
  u16x4 a = *(const u16x4*)(rout + (long)p0 * H_DIM + c * 4);
  u16x4 b = *(const u16x4*)(rout + (long)p1 * H_DIM + c * 4);
  f32x4* o = (f32x4*)out + (long)tkn * 256;
  f32x4 v = o[c];
  #pragma unroll
  for (int j = 0; j < 4; ++j) v[j] += bf2f(a[j]) + bf2f(b[j]);
  o[c] = v;
}

// ---------------------------------------------------------------- grouped GEMM1
// Flat grid, mt-major mapping (r13-proven). 128x128 tile, BK=32, 512 thr /
// 8 waves (2Mx4N, acc[4][2]), 32KB LDS, 2-phase. A rows resolved once per
// thread via btok (gather fused). C = gelu(A@B^T + bias) bf16. K=1024, N=4096.
__global__ __launch_bounds__(512)
void moe_gemm1(const unsigned short* __restrict__ x_bf,
               const unsigned short* __restrict__ Wsh, const unsigned short* __restrict__ Wrt,
               const float* __restrict__ bsh, const float* __restrict__ brt,
               unsigned short* __restrict__ Csh, unsigned short* __restrict__ Crt,
               const int* __restrict__ btok,
               const int* __restrict__ cnts, const int* __restrict__ offs,
               const int* __restrict__ tt) {
  __shared__ __align__(16) unsigned short lds[2][2][128][32];   // 32 KB
  const int wid = xcd_swizzle(blockIdx.x, G1_GRID);
  const int mt = wid >> 5, nb = wid & 31;
  if (mt >= tt[9]) return;
  int z = 0;
  while (mt >= tt[z + 1]) ++z;
  const int mlocal = mt - tt[z];

  const unsigned short* Bp;
  const float* bias;
  unsigned short* C;
  int mcnt;
  const unsigned short* srcA;
  const int t = threadIdx.x;
  {
    const int r0 = mlocal * 128 + (t >> 2);
    if (z == NEXP) {
      Bp = Wsh; bias = bsh; C = Csh; mcnt = T_TOK;
      srcA = x_bf + (long)r0 * H_DIM;
    } else {
      const int off = offs[z];
      mcnt = cnts[z];
      Bp = Wrt + (long)z * F_DIM * H_DIM;
      bias = brt + z * F_DIM;
      C = Crt + (long)off * F_DIM;
      int g0 = off + r0;
      if (g0 > RT - 1) g0 = RT - 1;            // clamped: tail rows epilogue-masked
      srcA = x_bf + (long)btok[g0] * H_DIM;
    }
  }

  f32x4 acc[4][2] = {};
  const int nk = H_DIM >> 5;   // 32 K-steps
  const int ch = (t & 3) * 8;

  auto stage = [&](int kt, int buf) {
    const int row = t >> 2;
    const unsigned short* ga = srcA + kt * 32 + ch;
    const unsigned short* gb = Bp + (long)(nb * 128 + row) * H_DIM + kt * 32 + ch;
    unsigned short* la = &lds[buf][0][0][0] + t * 8;
    unsigned short* lb = &lds[buf][1][0][0] + t * 8;
    __builtin_amdgcn_global_load_lds((const __attribute__((address_space(1))) unsigned int*)ga,
                                     (__attribute__((address_space(3))) unsigned int*)la, 16, 0, 0);
    __builtin_amdgcn_global_load_lds((const __attribute__((address_space(1))) unsigned int*)gb,
                                     (__attribute__((address_space(3))) unsigned int*)lb, 16, 0, 0);
  };

  const int l = t & 63;
  const int w = t >> 6;                       // 8 waves: 2M x 4N
  const int wr = (w >> 2) * 64, wc = (w & 3) * 32;
  const int lr = l & 15, lk = (l >> 4) * 8;

  auto compute = [&](int buf) {
    bf16x8 a[4], b[2];
    #pragma unroll
    for (int m = 0; m < 4; ++m) a[m] = *(const bf16x8*)&lds[buf][0][wr + m * 16 + lr][lk];
    #pragma unroll
    for (int n = 0; n < 2; ++n) b[n] = *(const bf16x8*)&lds[buf][1][wc + n * 16 + lr][lk];
    #pragma unroll
    for (int m = 0; m < 4; ++m)
      #pragma unroll
      for (int n = 0; n < 2; ++n)
        acc[m][n] = __builtin_amdgcn_mfma_f32_16x16x32_bf16(a[m], b[n], acc[m][n], 0, 0, 0);
  };

  stage(0, 0);
  asm volatile("s_waitcnt vmcnt(0)" ::: "memory");
  __syncthreads();
  for (int kt = 0; kt < nk - 1; ++kt) {
    const int cur = kt & 1;
    stage(kt + 1, cur ^ 1);
    compute(cur);
    asm volatile("s_waitcnt vmcnt(0)" ::: "memory");
    __syncthreads();
  }
  compute((nk - 1) & 1);

  // epilogue: C/D layout col=lane&15, row=(lane>>4)*4+j (m89-verified)
  #pragma unroll
  for (int m = 0; m < 4; ++m) {
    #pragma unroll
    for (int n = 0; n < 2; ++n) {
      const int col = nb * 128 + wc + n * 16 + lr;
      const float bc = bias[col];
      #pragma unroll
      for (int j = 0; j < 4; ++j) {
        const int lrow = mlocal * 128 + wr + m * 16 + (l >> 4) * 4 + j;
        if (lrow >= mcnt) continue;
        float v = acc[m][n][j] + bc;
        C[(long)lrow * F_DIM + col] = f2bf(gelu_exact(v));
      }
    }
  }
}

// ---------------------------------------------------------------- grouped GEMM2
// Flat grid, mt-major mapping (r13-proven). 128x128, BK=32, 8 waves (512 thr,
// 2Mx4N, acc[4][2]), 2-phase. shared -> out (f32); routed -> rout (bf16, *bw).
// K=4096, N=1024, NB=8.
__global__ __launch_bounds__(512)
void moe_gemm2(const unsigned short* __restrict__ hbuf,
               const unsigned short* __restrict__ Wsh, const unsigned short* __restrict__ Wrt,
               const float* __restrict__ bsh, const float* __restrict__ brt,
               float* __restrict__ out, unsigned short* __restrict__ rout,
               const float* __restrict__ bwgt,
               const int* __restrict__ cnts, const int* __restrict__ offs,
               const int* __restrict__ tt) {
  __shared__ __align__(16) unsigned short lds[2][2][128][32];   // 32 KB
  const int wid = xcd_swizzle(blockIdx.x, G2_GRID);
  const int mt = wid >> 3, nb = wid & 7;
  if (mt >= tt[9]) return;
  int z = 0;
  while (mt >= tt[z + 1]) ++z;
  const int mlocal = mt - tt[z];

  const unsigned short* A;
  const unsigned short* Bp;
  const float* bias;
  const float* rs = nullptr;
  unsigned short* Crt = nullptr;
  int mcnt;
  if (z == NEXP) {
    A = hbuf; Bp = Wsh; bias = bsh; mcnt = T_TOK;
  } else {
    const int off = offs[z];
    mcnt = cnts[z];
    A = hbuf + ((long)T_TOK + off) * F_DIM;
    Bp = Wrt + (long)z * H_DIM * F_DIM;
    bias = brt + z * H_DIM;
    Crt = rout + (long)off * H_DIM;
    rs = bwgt + off;
  }

  const int t = threadIdx.x;
  f32x4 acc[4][2] = {};
  const int nk = F_DIM >> 5;   // 128 K-steps

  auto stage = [&](int kt, int buf) {
    const int row = t >> 2;
    const int ch = (t & 3) * 8;
    const unsigned short* ga = A + (long)(mlocal * 128 + row) * F_DIM + kt * 32 + ch;
    const unsigned short* gb = Bp + (long)(nb * 128 + row) * F_DIM + kt * 32 + ch;
    unsigned short* la = &lds[buf][0][0][0] + t * 8;
    unsigned short* lb = &lds[buf][1][0][0] + t * 8;
    __builtin_amdgcn_global_load_lds((const __attribute__((address_space(1))) unsigned int*)ga,
                                     (__attribute__((address_space(3))) unsigned int*)la, 16, 0, 0);
    __builtin_amdgcn_global_load_lds((const __attribute__((address_space(1))) unsigned int*)gb,
                                     (__attribute__((address_space(3))) unsigned int*)lb, 16, 0, 0);
  };

  const int l = t & 63;
  const int w = t >> 6;                       // 8 waves: 2M x 4N
  const int wr = (w >> 2) * 64, wc = (w & 3) * 32;
  const int lr = l & 15, lk = (l >> 4) * 8;

  auto compute = [&](int buf) {
    bf16x8 a[4], b[2];
    #pragma unroll
    for (int m = 0; m < 4; ++m) a[m] = *(const bf16x8*)&lds[buf][0][wr + m * 16 + lr][lk];
    #pragma unroll
    for (int n = 0; n < 2; ++n) b[n] = *(const bf16x8*)&lds[buf][1][wc + n * 16 + lr][lk];
    #pragma unroll
    for (int m = 0; m < 4; ++m)
      #pragma unroll
      for (int n = 0; n < 2; ++n)
        acc[m][n] = __builtin_amdgcn_mfma_f32_16x16x32_bf16(a[m], b[n], acc[m][n], 0, 0, 0);
  };

  stage(0, 0);
  asm volatile("s_waitcnt vmcnt(0)" ::: "memory");
  __syncthreads();
  for (int kt = 0; kt < nk - 1; ++kt) {
    const int cur = kt & 1;
    stage(kt + 1, cur ^ 1);
    compute(cur);
    asm volatile("s_waitcnt vmcnt(0)" ::: "memory");
    __syncthreads();
  }
  compute((nk - 1) & 1);

  const bool routed = (z != NEXP);
  #pragma unroll
  for (int m = 0; m < 4; ++m) {
    #pragma unroll
    for (int n = 0; n < 2; ++n) {
      const int col = nb * 128 + wc + n * 16 + lr;
      const float bc = bias[col];
      #pragma unroll
      for (int j = 0; j < 4; ++j) {
        const int lrow = mlocal * 128 + wr + m * 16 + (l >> 4) * 4 + j;
        if (lrow >= mcnt) continue;
        float v = acc[m][n][j] + bc;
        if (routed) Crt[(long)lrow * H_DIM + col] = f2bf(v * rs[lrow]);
        else        out[(long)lrow * H_DIM + col] = v;
      }
    }
  }
}

// ---------------------------------------------------------------- host

extern "C" void kernel_launch(void* const* d_in, const int* in_sizes, int n_in,
                              void* d_out, int out_size, void* d_ws, size_t ws_size,
                              hipStream_t stream) {
  const float* x   = (const float*)d_in[0];
  const float* gw  = (const float*)d_in[1];
  const float* gb  = (const float*)d_in[2];
  const float* rb  = (const float*)d_in[3];
  const float* sw1 = (const float*)d_in[4];
  const float* sb1 = (const float*)d_in[5];
  const float* sw2 = (const float*)d_in[6];
  const float* sb2 = (const float*)d_in[7];
  const float* ew1 = (const float*)d_in[8];
  const float* eb1 = (const float*)d_in[9];
  const float* ew2 = (const float*)d_in[10];
  const float* eb2 = (const float*)d_in[11];

  char* wsp = (char*)d_ws;
  size_t o = 0;
  auto alloc = [&](size_t b) -> void* {
    void* p = wsp + o;
    o = (o + b + 255) & ~(size_t)255;
    return p;
  };
  unsigned short* x_bf = (unsigned short*)alloc((size_t)T_TOK * H_DIM * 2);
  // w1s|w2s|w1e|w2e contiguous (convert4 writes one flat dst)
  unsigned short* w1s  = (unsigned short*)alloc((size_t)F_DIM * H_DIM * 2);
  unsigned short* w2s  = (unsigned short*)alloc((size_t)H_DIM * F_DIM * 2);
  unsigned short* w1e  = (unsigned short*)alloc((size_t)NEXP * F_DIM * H_DIM * 2);
  unsigned short* w2e  = (unsigned short*)alloc((size_t)NEXP * H_DIM * F_DIM * 2);
  unsigned short* hbuf = (unsigned short*)alloc((size_t)(T_TOK + RT + RPAD) * F_DIM * 2);
  unsigned short* rout = (unsigned short*)alloc((size_t)RT * H_DIM * 2);
  int*   tok_e  = (int*)alloc(2 * T_TOK * 4);
  float* tok_w  = (float*)alloc(2 * T_TOK * 4);
  int*   tokpos = (int*)alloc(2 * T_TOK * 4);
  int*   btok   = (int*)alloc(RT * 4);
  float* bw     = (float*)alloc(RT * 4);
  int*   meta   = (int*)alloc(1024);
  int* counts = meta, *offs = meta + 16;
  int* ttof = meta + 32;
  (void)ws_size; (void)in_sizes; (void)n_in; (void)out_size;

  float* out = (float*)d_out;

  convert4_kernel<<<4096, 256, 0, stream>>>(sw1, sw2, ew1, ew2, w1s, meta);
  gate_kernel<<<T_TOK, 64, 0, stream>>>(x, gw, gb, rb, x_bf, tok_e, tok_w, counts);
  scanbuild_kernel<<<1, 256, 0, stream>>>(counts, tok_e, tok_w, offs, ttof,
                                          btok, bw, tokpos);

  // GEMM1: K=1024, N=4096; 128^2 8-wave; gather fused; mt-major mapping.
  moe_gemm1<<<G1_GRID, 512, 0, stream>>>(
      x_bf, w1s, w1e, sb1, eb1,
      hbuf, hbuf + (size_t)T_TOK * F_DIM, btok, counts, offs, ttof);

  // GEMM2: K=4096, N=1024; 128^2 8-wave; mt-major mapping; routed out bf16.
  moe_gemm2<<<G2_GRID, 512, 0, stream>>>(
      hbuf, w2s, w2e, sb2, eb2, out, rout, bw, counts, offs, ttof);

  combine_kernel<<<T_TOK, 256, 0, stream>>>(out, rout, tokpos);
}

// Round 19
// 446.231 us; speedup vs baseline: 1.2179x; 1.2092x over previous
//
#include <hip/hip_runtime.h>
#include <hip/hip_bf16.h>
#include <math.h>

// DeepSeekMoE: T=4096, H=1024, F=4096, E=8, top-2 sigmoid routing.
// Round 19: r16/r18 base (538us best). Final trim: convert+gate fused into ONE
// heterogeneous dispatch (blocks 0-1023 = gate, 4 waves/block; blocks
// 1024-5119 = weight convert grid-stride) -- the two are data-independent, so
// gate's ~16us hides under the BW-bound convert. Counts moved into scanbuild
// (LDS histogram over tok_e) -> no global counts zeroing, no race, meta-zero
// deleted. GEMMs identical to r16 (128^2/8-wave/mt-major, measured optimum).
// Closed lanes: 8-phase (r4/r6/m232), fused convert-into-GEMM (r5/r8-r10),
// atomic combine (r11), 64^2 tile (r14), B-panel-major (r15), L3-warm (r17).

#define T_TOK 4096
#define H_DIM 1024
#define F_DIM 4096
#define NEXP  8
#define RT    (2 * T_TOK)
#define RPAD  512

// worst-case flat grid sizes (fixed for graph capture); BM=128 tiles: 32 shared
// + max 72 expert M-tiles = 104.
#define GT_TILES 104
#define G1_GRID  (GT_TILES * 32)   // NB1 = F/128 = 32
#define G2_GRID  (GT_TILES * 8)    // NB2 = H/128 = 8

#define GATE_BLOCKS (T_TOK / 4)    // 1024 (4 tokens per 256-thr block)
#define CONV_BLOCKS 4096
#define PREP_GRID   (GATE_BLOCKS + CONV_BLOCKS)

typedef __bf16 bf16_t;
typedef __bf16 bf16x8 __attribute__((ext_vector_type(8)));
typedef float  f32x4  __attribute__((ext_vector_type(4)));
typedef unsigned short u16x8 __attribute__((ext_vector_type(8)));
typedef unsigned short u16x4 __attribute__((ext_vector_type(4)));

__device__ __forceinline__ unsigned short f2bf(float f) {
  union { bf16_t b; unsigned short u; } cv;
  cv.b = (bf16_t)f;
  return cv.u;
}

__device__ __forceinline__ float bf2f(unsigned short u) {
  union { bf16_t b; unsigned short u; } cv;
  cv.u = u;
  return (float)cv.b;
}

__device__ __forceinline__ float gelu_exact(float v) {
  return 0.5f * v * (1.0f + erff(v * 0.70710678118654752f));
}

// bijective XCD swizzle (m204)
__device__ __forceinline__ int xcd_swizzle(int orig, int nwg) {
  const int q = nwg >> 3, r = nwg & 7;
  const int xcd = orig & 7, idx = orig >> 3;
  return (xcd < r ? xcd * (q + 1) : r * (q + 1) + (xcd - r) * q) + idx;
}

// ---------------------------------------------------------------- prep kernel
// blocks [0, GATE_BLOCKS): gate -- 4 waves/block, one token per wave:
//   8 gate scores -> sigmoid -> top2; emits x_bf. NO global counts (scanbuild
//   histograms tok_e instead).
// blocks [GATE_BLOCKS, PREP_GRID): weight convert fp32->bf16, grid-stride over
//   w1s|w2s|w1e|w2e as one flat contiguous dst.
__global__ __launch_bounds__(256)
void prep_kernel(const float* __restrict__ x, const float* __restrict__ gw,
                 const float* __restrict__ gb, const float* __restrict__ rb,
                 unsigned short* __restrict__ x_bf,
                 int* __restrict__ tok_e, float* __restrict__ tok_w,
                 const float* __restrict__ s0, const float* __restrict__ s1,
                 const float* __restrict__ s2, const float* __restrict__ s3,
                 unsigned short* __restrict__ dst) {
  const int t = threadIdx.x;
  if (blockIdx.x < GATE_BLOCKS) {
    // ---- gate path: wave w handles token blockIdx.x*4 + w
    const int lane = t & 63;
    const int tkn = blockIdx.x * 4 + (t >> 6);
    float acc[NEXP];
    #pragma unroll
    for (int e = 0; e < NEXP; ++e) acc[e] = 0.f;
    const float* xr = x + (long)tkn * H_DIM;
    unsigned short* xbr = x_bf + (long)tkn * H_DIM;
    for (int k = lane; k < H_DIM; k += 64) {
      float xv = xr[k];
      xbr[k] = f2bf(xv);
      #pragma unroll
      for (int e = 0; e < NEXP; ++e) acc[e] += xv * gw[e * H_DIM + k];
    }
    #pragma unroll
    for (int off = 32; off > 0; off >>= 1) {
      #pragma unroll
      for (int e = 0; e < NEXP; ++e) acc[e] += __shfl_xor(acc[e], off, 64);
    }
    if (lane == 0) {
      float s[NEXP];
      #pragma unroll
      for (int e = 0; e < NEXP; ++e)
        s[e] = 1.f / (1.f + expf(-(acc[e] + gb[e] + rb[e])));
      int e0 = 0;
      #pragma unroll
      for (int e = 1; e < NEXP; ++e) if (s[e] > s[e0]) e0 = e;
      int e1 = (e0 == 0) ? 1 : 0;
      #pragma unroll
      for (int e = 0; e < NEXP; ++e) if (e != e0 && e != e1 && s[e] > s[e1]) e1 = e;
      tok_e[2 * tkn] = e0;  tok_e[2 * tkn + 1] = e1;
      tok_w[2 * tkn] = s[e0]; tok_w[2 * tkn + 1] = s[e1];
    }
  } else {
    // ---- convert path
    const long N0 = (long)F_DIM * H_DIM / 8;
    const long N1 = N0 + (long)H_DIM * F_DIM / 8;
    const long N2 = N1 + (long)NEXP * F_DIM * H_DIM / 8;
    const long NT = N2 + (long)NEXP * H_DIM * F_DIM / 8;
    long i = (long)(blockIdx.x - GATE_BLOCKS) * 256 + t;
    const long stride = (long)CONV_BLOCKS * 256;
    for (; i < NT; i += stride) {
      const float* s; long j;
      if (i < N0)      { s = s0; j = i; }
      else if (i < N1) { s = s1; j = i - N0; }
      else if (i < N2) { s = s2; j = i - N1; }
      else             { s = s3; j = i - N2; }
      const f32x4* sp = (const f32x4*)s + j * 2;
      f32x4 v0 = sp[0], v1 = sp[1];
      u16x8 o;
      #pragma unroll
      for (int k = 0; k < 4; ++k) { o[k] = f2bf(v0[k]); o[4 + k] = f2bf(v1[k]); }
      *(u16x8*)(dst + i * 8) = o;
    }
  }
}

// merged count+scan+build: single block. Pass 1: LDS histogram of tok_e.
// Pass 2 (thread 0): scan -> offs + BM=128 tile table + global counts.
// Pass 3: bucket all tokens via LDS cursors.
__global__ void scanbuild_kernel(const int* __restrict__ tok_e, const float* __restrict__ tok_w,
                                 int* __restrict__ counts_g,
                                 int* __restrict__ offs_g, int* __restrict__ tt_g,
                                 int* __restrict__ btok, float* __restrict__ bw,
                                 int* __restrict__ tokpos) {
  __shared__ int cnt_s[NEXP], offs_s[NEXP], cur_s[NEXP];
  const int t = threadIdx.x;
  if (t < NEXP) { cnt_s[t] = 0; cur_s[t] = 0; }
  __syncthreads();
  for (int i = t; i < 2 * T_TOK; i += 256)
    atomicAdd(&cnt_s[tok_e[i]], 1);
  __syncthreads();
  if (t == 0) {
    int o = 0, a = 0;
    for (int e = 0; e < NEXP; ++e) {
      counts_g[e] = cnt_s[e];
      offs_s[e] = o; offs_g[e] = o;
      tt_g[e] = a;
      a += (cnt_s[e] + 127) >> 7;
      o += cnt_s[e];
    }
    tt_g[8] = a;
    tt_g[9] = a + (T_TOK >> 7);
  }
  __syncthreads();
  for (int tkn = t; tkn < T_TOK; tkn += 256) {
    #pragma unroll
    for (int k = 0; k < 2; ++k) {
      int e = tok_e[2 * tkn + k];
      int p = offs_s[e] + atomicAdd(&cur_s[e], 1);
      btok[p] = tkn;
      bw[p] = tok_w[2 * tkn + k];
      tokpos[2 * tkn + k] = p;
    }
  }
}

// out += rout_bf16[p0] + rout_bf16[p1]  (f32 accumulate)
__global__ void combine_kernel(float* __restrict__ out, const unsigned short* __restrict__ rout,
                               const int* __restrict__ tokpos) {
  int tkn = blockIdx.x, c = threadIdx.x;   // 256 threads * 4 elems
  int p0 = tokpos[2 * tkn], p1 = tokpos[2 * tkn + 1];
  u16x4 a = *(const u16x4*)(rout + (long)p0 * H_DIM + c * 4);
  u16x4 b = *(const u16x4*)(rout + (long)p1 * H_DIM + c * 4);
  f32x4* o = (f32x4*)out + (long)tkn * 256;
  f32x4 v = o[c];
  #pragma unroll
  for (int j = 0; j < 4; ++j) v[j] += bf2f(a[j]) + bf2f(b[j]);
  o[c] = v;
}

// ---------------------------------------------------------------- grouped GEMM1
// Flat grid, mt-major mapping (r13-proven). 128x128 tile, BK=32, 512 thr /
// 8 waves (2Mx4N, acc[4][2]), 32KB LDS, 2-phase. A rows resolved once per
// thread via btok (gather fused). C = gelu(A@B^T + bias) bf16. K=1024, N=4096.
__global__ __launch_bounds__(512)
void moe_gemm1(const unsigned short* __restrict__ x_bf,
               const unsigned short* __restrict__ Wsh, const unsigned short* __restrict__ Wrt,
               const float* __restrict__ bsh, const float* __restrict__ brt,
               unsigned short* __restrict__ Csh, unsigned short* __restrict__ Crt,
               const int* __restrict__ btok,
               const int* __restrict__ cnts, const int* __restrict__ offs,
               const int* __restrict__ tt) {
  __shared__ __align__(16) unsigned short lds[2][2][128][32];   // 32 KB
  const int wid = xcd_swizzle(blockIdx.x, G1_GRID);
  const int mt = wid >> 5, nb = wid & 31;
  if (mt >= tt[9]) return;
  int z = 0;
  while (mt >= tt[z + 1]) ++z;
  const int mlocal = mt - tt[z];

  const unsigned short* Bp;
  const float* bias;
  unsigned short* C;
  int mcnt;
  const unsigned short* srcA;
  const int t = threadIdx.x;
  {
    const int r0 = mlocal * 128 + (t >> 2);
    if (z == NEXP) {
      Bp = Wsh; bias = bsh; C = Csh; mcnt = T_TOK;
      srcA = x_bf + (long)r0 * H_DIM;
    } else {
      const int off = offs[z];
      mcnt = cnts[z];
      Bp = Wrt + (long)z * F_DIM * H_DIM;
      bias = brt + z * F_DIM;
      C = Crt + (long)off * F_DIM;
      int g0 = off + r0;
      if (g0 > RT - 1) g0 = RT - 1;            // clamped: tail rows epilogue-masked
      srcA = x_bf + (long)btok[g0] * H_DIM;
    }
  }

  f32x4 acc[4][2] = {};
  const int nk = H_DIM >> 5;   // 32 K-steps
  const int ch = (t & 3) * 8;

  auto stage = [&](int kt, int buf) {
    const int row = t >> 2;
    const unsigned short* ga = srcA + kt * 32 + ch;
    const unsigned short* gb = Bp + (long)(nb * 128 + row) * H_DIM + kt * 32 + ch;
    unsigned short* la = &lds[buf][0][0][0] + t * 8;
    unsigned short* lb = &lds[buf][1][0][0] + t * 8;
    __builtin_amdgcn_global_load_lds((const __attribute__((address_space(1))) unsigned int*)ga,
                                     (__attribute__((address_space(3))) unsigned int*)la, 16, 0, 0);
    __builtin_amdgcn_global_load_lds((const __attribute__((address_space(1))) unsigned int*)gb,
                                     (__attribute__((address_space(3))) unsigned int*)lb, 16, 0, 0);
  };

  const int l = t & 63;
  const int w = t >> 6;                       // 8 waves: 2M x 4N
  const int wr = (w >> 2) * 64, wc = (w & 3) * 32;
  const int lr = l & 15, lk = (l >> 4) * 8;

  auto compute = [&](int buf) {
    bf16x8 a[4], b[2];
    #pragma unroll
    for (int m = 0; m < 4; ++m) a[m] = *(const bf16x8*)&lds[buf][0][wr + m * 16 + lr][lk];
    #pragma unroll
    for (int n = 0; n < 2; ++n) b[n] = *(const bf16x8*)&lds[buf][1][wc + n * 16 + lr][lk];
    #pragma unroll
    for (int m = 0; m < 4; ++m)
      #pragma unroll
      for (int n = 0; n < 2; ++n)
        acc[m][n] = __builtin_amdgcn_mfma_f32_16x16x32_bf16(a[m], b[n], acc[m][n], 0, 0, 0);
  };

  stage(0, 0);
  asm volatile("s_waitcnt vmcnt(0)" ::: "memory");
  __syncthreads();
  for (int kt = 0; kt < nk - 1; ++kt) {
    const int cur = kt & 1;
    stage(kt + 1, cur ^ 1);
    compute(cur);
    asm volatile("s_waitcnt vmcnt(0)" ::: "memory");
    __syncthreads();
  }
  compute((nk - 1) & 1);

  // epilogue: C/D layout col=lane&15, row=(lane>>4)*4+j (m89-verified)
  #pragma unroll
  for (int m = 0; m < 4; ++m) {
    #pragma unroll
    for (int n = 0; n < 2; ++n) {
      const int col = nb * 128 + wc + n * 16 + lr;
      const float bc = bias[col];
      #pragma unroll
      for (int j = 0; j < 4; ++j) {
        const int lrow = mlocal * 128 + wr + m * 16 + (l >> 4) * 4 + j;
        if (lrow >= mcnt) continue;
        float v = acc[m][n][j] + bc;
        C[(long)lrow * F_DIM + col] = f2bf(gelu_exact(v));
      }
    }
  }
}

// ---------------------------------------------------------------- grouped GEMM2
// Flat grid, mt-major mapping (r13-proven). 128x128, BK=32, 8 waves (512 thr,
// 2Mx4N, acc[4][2]), 2-phase. shared -> out (f32); routed -> rout (bf16, *bw).
// K=4096, N=1024, NB=8.
__global__ __launch_bounds__(512)
void moe_gemm2(const unsigned short* __restrict__ hbuf,
               const unsigned short* __restrict__ Wsh, const unsigned short* __restrict__ Wrt,
               const float* __restrict__ bsh, const float* __restrict__ brt,
               float* __restrict__ out, unsigned short* __restrict__ rout,
               const float* __restrict__ bwgt,
               const int* __restrict__ cnts, const int* __restrict__ offs,
               const int* __restrict__ tt) {
  __shared__ __align__(16) unsigned short lds[2][2][128][32];   // 32 KB
  const int wid = xcd_swizzle(blockIdx.x, G2_GRID);
  const int mt = wid >> 3, nb = wid & 7;
  if (mt >= tt[9]) return;
  int z = 0;
  while (mt >= tt[z + 1]) ++z;
  const int mlocal = mt - tt[z];

  const unsigned short* A;
  const unsigned short* Bp;
  const float* bias;
  const float* rs = nullptr;
  unsigned short* Crt = nullptr;
  int mcnt;
  if (z == NEXP) {
    A = hbuf; Bp = Wsh; bias = bsh; mcnt = T_TOK;
  } else {
    const int off = offs[z];
    mcnt = cnts[z];
    A = hbuf + ((long)T_TOK + off) * F_DIM;
    Bp = Wrt + (long)z * H_DIM * F_DIM;
    bias = brt + z * H_DIM;
    Crt = rout + (long)off * H_DIM;
    rs = bwgt + off;
  }

  const int t = threadIdx.x;
  f32x4 acc[4][2] = {};
  const int nk = F_DIM >> 5;   // 128 K-steps

  auto stage = [&](int kt, int buf) {
    const int row = t >> 2;
    const int ch = (t & 3) * 8;
    const unsigned short* ga = A + (long)(mlocal * 128 + row) * F_DIM + kt * 32 + ch;
    const unsigned short* gb = Bp + (long)(nb * 128 + row) * F_DIM + kt * 32 + ch;
    unsigned short* la = &lds[buf][0][0][0] + t * 8;
    unsigned short* lb = &lds[buf][1][0][0] + t * 8;
    __builtin_amdgcn_global_load_lds((const __attribute__((address_space(1))) unsigned int*)ga,
                                     (__attribute__((address_space(3))) unsigned int*)la, 16, 0, 0);
    __builtin_amdgcn_global_load_lds((const __attribute__((address_space(1))) unsigned int*)gb,
                                     (__attribute__((address_space(3))) unsigned int*)lb, 16, 0, 0);
  };

  const int l = t & 63;
  const int w = t >> 6;                       // 8 waves: 2M x 4N
  const int wr = (w >> 2) * 64, wc = (w & 3) * 32;
  const int lr = l & 15, lk = (l >> 4) * 8;

  auto compute = [&](int buf) {
    bf16x8 a[4], b[2];
    #pragma unroll
    for (int m = 0; m < 4; ++m) a[m] = *(const bf16x8*)&lds[buf][0][wr + m * 16 + lr][lk];
    #pragma unroll
    for (int n = 0; n < 2; ++n) b[n] = *(const bf16x8*)&lds[buf][1][wc + n * 16 + lr][lk];
    #pragma unroll
    for (int m = 0; m < 4; ++m)
      #pragma unroll
      for (int n = 0; n < 2; ++n)
        acc[m][n] = __builtin_amdgcn_mfma_f32_16x16x32_bf16(a[m], b[n], acc[m][n], 0, 0, 0);
  };

  stage(0, 0);
  asm volatile("s_waitcnt vmcnt(0)" ::: "memory");
  __syncthreads();
  for (int kt = 0; kt < nk - 1; ++kt) {
    const int cur = kt & 1;
    stage(kt + 1, cur ^ 1);
    compute(cur);
    asm volatile("s_waitcnt vmcnt(0)" ::: "memory");
    __syncthreads();
  }
  compute((nk - 1) & 1);

  const bool routed = (z != NEXP);
  #pragma unroll
  for (int m = 0; m < 4; ++m) {
    #pragma unroll
    for (int n = 0; n < 2; ++n) {
      const int col = nb * 128 + wc + n * 16 + lr;
      const float bc = bias[col];
      #pragma unroll
      for (int j = 0; j < 4; ++j) {
        const int lrow = mlocal * 128 + wr + m * 16 + (l >> 4) * 4 + j;
        if (lrow >= mcnt) continue;
        float v = acc[m][n][j] + bc;
        if (routed) Crt[(long)lrow * H_DIM + col] = f2bf(v * rs[lrow]);
        else        out[(long)lrow * H_DIM + col] = v;
      }
    }
  }
}

// ---------------------------------------------------------------- host

extern "C" void kernel_launch(void* const* d_in, const int* in_sizes, int n_in,
                              void* d_out, int out_size, void* d_ws, size_t ws_size,
                              hipStream_t stream) {
  const float* x   = (const float*)d_in[0];
  const float* gw  = (const float*)d_in[1];
  const float* gb  = (const float*)d_in[2];
  const float* rb  = (const float*)d_in[3];
  const float* sw1 = (const float*)d_in[4];
  const float* sb1 = (const float*)d_in[5];
  const float* sw2 = (const float*)d_in[6];
  const float* sb2 = (const float*)d_in[7];
  const float* ew1 = (const float*)d_in[8];
  const float* eb1 = (const float*)d_in[9];
  const float* ew2 = (const float*)d_in[10];
  const float* eb2 = (const float*)d_in[11];

  char* wsp = (char*)d_ws;
  size_t o = 0;
  auto alloc = [&](size_t b) -> void* {
    void* p = wsp + o;
    o = (o + b + 255) & ~(size_t)255;
    return p;
  };
  unsigned short* x_bf = (unsigned short*)alloc((size_t)T_TOK * H_DIM * 2);
  // w1s|w2s|w1e|w2e contiguous (prep convert writes one flat dst)
  unsigned short* w1s  = (unsigned short*)alloc((size_t)F_DIM * H_DIM * 2);
  unsigned short* w2s  = (unsigned short*)alloc((size_t)H_DIM * F_DIM * 2);
  unsigned short* w1e  = (unsigned short*)alloc((size_t)NEXP * F_DIM * H_DIM * 2);
  unsigned short* w2e  = (unsigned short*)alloc((size_t)NEXP * H_DIM * F_DIM * 2);
  unsigned short* hbuf = (unsigned short*)alloc((size_t)(T_TOK + RT + RPAD) * F_DIM * 2);
  unsigned short* rout = (unsigned short*)alloc((size_t)RT * H_DIM * 2);
  int*   tok_e  = (int*)alloc(2 * T_TOK * 4);
  float* tok_w  = (float*)alloc(2 * T_TOK * 4);
  int*   tokpos = (int*)alloc(2 * T_TOK * 4);
  int*   btok   = (int*)alloc(RT * 4);
  float* bw     = (float*)alloc(RT * 4);
  int*   meta   = (int*)alloc(1024);
  int* counts = meta, *offs = meta + 16;
  int* ttof = meta + 32;
  (void)ws_size; (void)in_sizes; (void)n_in; (void)out_size;

  float* out = (float*)d_out;

  // fused gate + weight convert (data-independent halves, one dispatch)
  prep_kernel<<<PREP_GRID, 256, 0, stream>>>(
      x, gw, gb, rb, x_bf, tok_e, tok_w, sw1, sw2, ew1, ew2, w1s);

  // count (LDS histogram) + scan + bucket build, single block
  scanbuild_kernel<<<1, 256, 0, stream>>>(tok_e, tok_w, counts, offs, ttof,
                                          btok, bw, tokpos);

  // GEMM1: K=1024, N=4096; 128^2 8-wave; gather fused; mt-major mapping.
  moe_gemm1<<<G1_GRID, 512, 0, stream>>>(
      x_bf, w1s, w1e, sb1, eb1,
      hbuf, hbuf + (size_t)T_TOK * F_DIM, btok, counts, offs, ttof);

  // GEMM2: K=4096, N=1024; 128^2 8-wave; mt-major mapping; routed out bf16.
  moe_gemm2<<<G2_GRID, 512, 0, stream>>>(
      hbuf, w2s, w2e, sb2, eb2, out, rout, bw, counts, offs, ttof);

  combine_kernel<<<T_TOK, 256, 0, stream>>>(out, rout, tokpos);
}